// Round 14
// baseline (203.993 us; speedup 1.0000x reference)
//
#include <hip/hip_runtime.h>
#include <cstdint>
#include <cstddef>

// ---------------------------------------------------------------------------
// GCN 3-conv + MLP head. FP16 single-product MFMA GEMMs (f32 accumulate),
// f16 activations, aggregate-before-linear (A(xW) == (Ax)W, Fin<Fout).
// All conv/fc GEMMs: 128x128 4-wave tiles. fc2 GEMM fuses bias+log_softmax.
// Single packed-u64 degree histogram (planar replication reverted: measured
// neutral, costs traffic); CSR slots from atomic returns; atomic-free fill.
// Round 14: dual-accumulator 8-edge-unrolled agg (isolated round-9 suspect).
// ---------------------------------------------------------------------------

typedef _Float16 f16;
typedef _Float16 half8 __attribute__((ext_vector_type(8)));
typedef _Float16 half4 __attribute__((ext_vector_type(4)));
typedef float v4f __attribute__((ext_vector_type(4)));
typedef unsigned long long u64;

__device__ inline void gload_lds16(const void* g, void* l) {
    __builtin_amdgcn_global_load_lds(
        (const __attribute__((address_space(1))) unsigned int*)g,
        (__attribute__((address_space(3))) unsigned int*)l, 16, 0, 0);
}

// ------------------------------ graph prep --------------------------------

// one packed atomic per edge; old value -> CSR slot within dst bucket
__global__ __launch_bounds__(256) void k_edge1(const int* __restrict__ dst, const float* __restrict__ ew,
                                               u64* __restrict__ packed, int* __restrict__ eslot, int E) {
    int t = blockIdx.x * blockDim.x + threadIdx.x;
    int e0 = t * 4;
    if (e0 + 3 < E) {
        int4 d4 = *(const int4*)(dst + e0);
        float4 w4 = *(const float4*)(ew + e0);
        u64 a0 = ((u64)__float2uint_rn(w4.x * 1048576.f) << 24) | 1ULL;
        u64 a1 = ((u64)__float2uint_rn(w4.y * 1048576.f) << 24) | 1ULL;
        u64 a2 = ((u64)__float2uint_rn(w4.z * 1048576.f) << 24) | 1ULL;
        u64 a3 = ((u64)__float2uint_rn(w4.w * 1048576.f) << 24) | 1ULL;
        u64 o0 = atomicAdd(&packed[d4.x], a0);
        u64 o1 = atomicAdd(&packed[d4.y], a1);
        u64 o2 = atomicAdd(&packed[d4.z], a2);
        u64 o3 = atomicAdd(&packed[d4.w], a3);
        int4 s;
        s.x = (int)(o0 & 0xFFFFFF); s.y = (int)(o1 & 0xFFFFFF);
        s.z = (int)(o2 & 0xFFFFFF); s.w = (int)(o3 & 0xFFFFFF);
        *(int4*)(eslot + e0) = s;
    } else {
        for (int e = e0; e < E; ++e) {
            u64 a = ((u64)__float2uint_rn(ew[e] * 1048576.f) << 24) | 1ULL;
            u64 o = atomicAdd(&packed[dst[e]], a);
            eslot[e] = (int)(o & 0xFFFFFF);
        }
    }
}

// fused: dinv (Newton-refined rsqrt of unpacked degree) + per-block cnt sums
__global__ __launch_bounds__(256) void k_dinv_scan1(const u64* __restrict__ packed,
                                                    float* __restrict__ dinv, int* __restrict__ cnt,
                                                    int* __restrict__ bsum, int n) {
    int i = blockIdx.x * 256 + threadIdx.x;
    int c = 0;
    if (i < n) {
        u64 pk = packed[i];
        c = (int)(pk & 0xFFFFFF);
        float d = 1.0f + (float)(pk >> 24) * (1.0f / 1048576.f);  // self-loop + sum(ew)
        float r = rsqrtf(d);
        r = r * (1.5f - 0.5f * d * r * r);
        dinv[i] = r;
        cnt[i] = c;
    }
    int v = c;
#pragma unroll
    for (int o = 32; o; o >>= 1) v += __shfl_xor(v, o);
    __shared__ int s[4];
    if ((threadIdx.x & 63) == 0) s[threadIdx.x >> 6] = v;
    __syncthreads();
    if (threadIdx.x == 0) bsum[blockIdx.x] = s[0] + s[1] + s[2] + s[3];
}

// 256-thread inclusive block scan (shfl wave scan + LDS wave offsets).
__device__ inline int block_scan_incl(int v) {
    __shared__ int ws[4];
    int lane = threadIdx.x & 63, w = threadIdx.x >> 6;
#pragma unroll
    for (int off = 1; off < 64; off <<= 1) {
        int t = __shfl_up(v, off);
        if (lane >= off) v += t;
    }
    if (lane == 63) ws[w] = v;
    __syncthreads();
    int add = 0;
#pragma unroll
    for (int i = 0; i < 4; ++i) add += (i < w) ? ws[i] : 0;
    __syncthreads();
    return v + add;
}

// fused scan2+scan3: each block sums bsum[0..blk) itself (one wave), then
// local scan + offset -> rowptr. No inter-block communication.
__global__ __launch_bounds__(256) void k_scan23(const int* __restrict__ cnt, const int* __restrict__ bsum,
                                                int* __restrict__ rowptr, int n, int E) {
    int blk = blockIdx.x, tid = threadIdx.x;
    int i = blk * 256 + tid;
    __shared__ int spre;
    if (tid < 64) {
        int s = 0;
        for (int j = tid; j < blk; j += 64) s += bsum[j];
#pragma unroll
        for (int o = 32; o; o >>= 1) s += __shfl_xor(s, o);
        if (tid == 0) spre = s;
    }
    __syncthreads();
    int v = (i < n) ? cnt[i] : 0;
    int incl = block_scan_incl(v);
    if (i < n) rowptr[i] = spre + incl - v;
    if (i == n - 1) rowptr[n] = E;
}

// atomic-free CSR fill using precomputed slots; f16 norm
__global__ __launch_bounds__(256) void k_fill(const int* __restrict__ src, const int* __restrict__ dst,
                                              const float* __restrict__ ew, const int* __restrict__ eslot,
                                              const float* __restrict__ dinv, const int* __restrict__ rowptr,
                                              int* __restrict__ csr_src, f16* __restrict__ csr_norm, int E) {
    int e = blockIdx.x * blockDim.x + threadIdx.x;
    if (e < E) {
        int d = dst[e], s = src[e];
        int idx = rowptr[d] + eslot[e];
        csr_src[idx] = s;
        csr_norm[idx] = (f16)(dinv[s] * ew[e] * dinv[d]);
    }
}

// fused: packed init + x f32->f16 cast + 5 weight transposes W[K,N]->WT[Np,K].
// Transpose reads COALESCED (k=li/Np, nr=li%Np); strided f16 writes merge in L2.
struct PrepArgs {
    u64* packed; int n;
    const float* x; f16* xh; int xt4;
    const float* W[5]; f16* WT[5];
    int lgK[5]; int lgNp[5]; int N[5]; int off[6];
};
__global__ __launch_bounds__(256) void k_prep(PrepArgs a) {
    int i = blockIdx.x * 256 + threadIdx.x;
    if (i < a.n) { a.packed[i] = 0ULL; return; }
    int j = i - a.n;
    if (j < a.xt4) {
        float4 v = *(const float4*)(a.x + (size_t)j * 4);
        half4 h = {(f16)v.x, (f16)v.y, (f16)v.z, (f16)v.w};
        *(half4*)(a.xh + (size_t)j * 4) = h;
        return;
    }
    int w = j - a.xt4;
#pragma unroll
    for (int s = 0; s < 5; ++s) {
        if (w >= a.off[s] && w < a.off[s + 1]) {
            int li = w - a.off[s];
            int Np = 1 << a.lgNp[s];
            int K = 1 << a.lgK[s];
            int k = li >> a.lgNp[s], nr = li & (Np - 1);
            float v = (nr < a.N[s]) ? a.W[s][(size_t)k * a.N[s] + nr] : 0.f;
            a.WT[s][(size_t)nr * K + k] = (f16)v;
        }
    }
}

// ------------------------------ aggregation -------------------------------
// out[i,:] = dinv[i]^2*h[i,:] + sum_j norm_j*h[src_j,:]; f16 in/out, f32 acc.
// Dual accumulators + 8-edge unroll: 8 independent 16B gathers in flight per
// lane, FMA chain split across two acc banks (isolated round-9 suspect).
template <int F>
__global__ __launch_bounds__(256) void k_agg(const f16* __restrict__ h,
                                             const float* __restrict__ dinv, const int* __restrict__ rowptr,
                                             const int* __restrict__ csr_src, const f16* __restrict__ csr_norm,
                                             f16* __restrict__ o, int n) {
    constexpr int LPN = F / 8;
    constexpr int NPW = 64 / LPN;
    int wave = (int)((blockIdx.x * (unsigned)blockDim.x + threadIdx.x) >> 6);
    int lane = threadIdx.x & 63;
    int grp = lane / LPN, lin = lane % LPN;
    int node = wave * NPW + grp;
    if (node >= n) return;
    float di = dinv[node], w0 = di * di;
    float acca[8], accb[8];
#pragma unroll
    for (int i = 0; i < 8; ++i) { acca[i] = 0.f; accb[i] = 0.f; }

    auto gat = [&](float* acc, int s, float w) {
        half8 x = *(const half8*)(h + (size_t)s * F + lin * 8);
#pragma unroll
        for (int i = 0; i < 8; ++i) acc[i] += w * (float)x[i];
    };

    gat(acca, node, w0);
    int beg = rowptr[node], end = rowptr[node + 1];
    int j = beg;
    for (; j + 7 < end; j += 8) {
        int s0 = csr_src[j], s1 = csr_src[j + 1], s2 = csr_src[j + 2], s3 = csr_src[j + 3];
        int s4 = csr_src[j + 4], s5 = csr_src[j + 5], s6 = csr_src[j + 6], s7 = csr_src[j + 7];
        float u0 = (float)csr_norm[j], u1 = (float)csr_norm[j + 1];
        float u2 = (float)csr_norm[j + 2], u3 = (float)csr_norm[j + 3];
        float u4 = (float)csr_norm[j + 4], u5 = (float)csr_norm[j + 5];
        float u6 = (float)csr_norm[j + 6], u7 = (float)csr_norm[j + 7];
        gat(acca, s0, u0); gat(accb, s1, u1); gat(acca, s2, u2); gat(accb, s3, u3);
        gat(acca, s4, u4); gat(accb, s5, u5); gat(acca, s6, u6); gat(accb, s7, u7);
    }
    for (; j + 1 < end; j += 2) {
        int s0 = csr_src[j], s1 = csr_src[j + 1];
        float u0 = (float)csr_norm[j], u1 = (float)csr_norm[j + 1];
        gat(acca, s0, u0); gat(accb, s1, u1);
    }
    if (j < end) gat(acca, csr_src[j], (float)csr_norm[j]);

    half8 v;
#pragma unroll
    for (int i = 0; i < 8; ++i) v[i] = (f16)(acca[i] + accb[i]);
    *(half8*)(o + (size_t)node * F + (size_t)lin * 8) = v;
}

// ------------------------------ MFMA GEMM ----------------------------------
// 128x128 tile, 4 waves 2x2. A,B via global_load_lds (XOR-swizzled both
// sides), double-buffered, one barrier per k-step. 64KB LDS -> 2 blocks/CU.
// Operand-swapped MFMA -> C^T frags -> coalesced 8B stores.
template <bool RELU>
__global__ __launch_bounds__(256) void k_mm(const f16* __restrict__ A, const f16* __restrict__ BT,
                                            const float* __restrict__ bias, f16* __restrict__ Ch,
                                            int M, int N, int K, int nB, int nwg) {
    __shared__ f16 lsA[2][128 * 64];
    __shared__ f16 lsB[2][128 * 64];
    int wg = blockIdx.x;
    int q = nwg >> 3, r = nwg & 7;
    int xcd = wg & 7, lin = wg >> 3;
    int wgs = (xcd < r) ? (xcd * (q + 1) + lin) : (r * (q + 1) + (xcd - r) * q + lin);
    int bm = wgs / nB, bn = wgs % nB;

    int tid = threadIdx.x;
    int lane = tid & 63, wid = tid >> 6;
    int l16 = lane & 15, lhi = lane >> 4;
    int wm = (wid >> 1) * 64, wn = (wid & 1) * 64;
    int brow = bm * 128, bcol = bn * 128;

    v4f acc[4][4] = {};

    auto stageA = [&](int buf, int k0) {
#pragma unroll
        for (int it = 0; it < 4; ++it) {
            int b = it * 4096 + tid * 16;
            int row = b >> 7;
            int s = ((b >> 4) & 7) ^ (row & 7);
            gload_lds16(A + (size_t)(brow + row) * K + k0 + s * 8, ((char*)&lsA[buf][0]) + b);
        }
    };
    auto stageB = [&](int buf, int k0) {
#pragma unroll
        for (int it = 0; it < 4; ++it) {
            int b = it * 4096 + tid * 16;
            int row = b >> 7;
            int s = ((b >> 4) & 7) ^ (row & 7);
            gload_lds16(BT + (size_t)(bcol + row) * K + k0 + s * 8, ((char*)&lsB[buf][0]) + b);
        }
    };

    int nk = K >> 6;
    stageA(0, 0);
    stageB(0, 0);
    for (int kt = 0; kt < nk; ++kt) {
        int cur = kt & 1;
        __syncthreads();  // buf[cur] DMA drained; prior LDS reads done
        if (kt + 1 < nk) { stageA(cur ^ 1, (kt + 1) << 6); stageB(cur ^ 1, (kt + 1) << 6); }
#pragma unroll
        for (int ks = 0; ks < 2; ++ks) {
            half8 bf[4];
#pragma unroll
            for (int fn = 0; fn < 4; ++fn) {
                int row = wn + fn * 16 + l16;
                int sidx = (ks * 4 + lhi) ^ (row & 7);
                bf[fn] = *(const half8*)(&lsB[cur][0] + row * 64 + sidx * 8);
            }
#pragma unroll
            for (int fm = 0; fm < 4; ++fm) {
                int row = wm + fm * 16 + l16;
                int sidx = (ks * 4 + lhi) ^ (row & 7);
                half8 af = *(const half8*)(&lsA[cur][0] + row * 64 + sidx * 8);
#pragma unroll
                for (int fn = 0; fn < 4; ++fn)
                    acc[fm][fn] = __builtin_amdgcn_mfma_f32_16x16x32_f16(bf[fn], af, acc[fm][fn], 0, 0, 0);
            }
        }
    }
#pragma unroll
    for (int fm = 0; fm < 4; ++fm) {
        int m = brow + wm + fm * 16 + l16;
        if (m >= M) continue;
#pragma unroll
        for (int fn = 0; fn < 4; ++fn) {
            int nb = bcol + wn + fn * 16 + lhi * 4;
            v4f bv = *(const v4f*)(bias + nb);
            v4f v = acc[fm][fn] + bv;
            if (RELU) {
#pragma unroll
                for (int rr = 0; rr < 4; ++rr) v[rr] = fmaxf(v[rr], 0.f);
            }
            half4 hv = {(f16)v[0], (f16)v[1], (f16)v[2], (f16)v[3]};
            *(half4*)(Ch + (size_t)m * N + nb) = hv;
        }
    }
}

// ----------------------- fc2 GEMM + log_softmax ---------------------------
__global__ __launch_bounds__(256) void k_mmfc2(const f16* __restrict__ A, const f16* __restrict__ BT,
                                               const float* __restrict__ bias, float* __restrict__ out,
                                               int M, int K) {
    __shared__ f16 lsA[2][256 * 64];
    __shared__ f16 lsB[2][64 * 64];
    int bm = blockIdx.x;
    int tid = threadIdx.x;
    int lane = tid & 63, wid = tid >> 6;
    int l16 = lane & 15, lhi = lane >> 4;
    int wm = wid * 64;
    int brow = bm * 256;

    v4f acc[4][4] = {};

    auto stageA = [&](int buf, int k0) {
#pragma unroll
        for (int it = 0; it < 8; ++it) {
            int b = it * 4096 + tid * 16;
            int row = b >> 7;
            int s = ((b >> 4) & 7) ^ (row & 7);
            gload_lds16(A + (size_t)(brow + row) * K + k0 + s * 8, ((char*)&lsA[buf][0]) + b);
        }
    };
    auto stageB = [&](int buf, int k0) {
#pragma unroll
        for (int it = 0; it < 2; ++it) {
            int b = it * 4096 + tid * 16;
            int row = b >> 7;
            int s = ((b >> 4) & 7) ^ (row & 7);
            gload_lds16(BT + (size_t)row * K + k0 + s * 8, ((char*)&lsB[buf][0]) + b);
        }
    };

    int nk = K >> 6;
    stageA(0, 0);
    stageB(0, 0);
    for (int kt = 0; kt < nk; ++kt) {
        int cur = kt & 1;
        __syncthreads();
        if (kt + 1 < nk) { stageA(cur ^ 1, (kt + 1) << 6); stageB(cur ^ 1, (kt + 1) << 6); }
#pragma unroll
        for (int ks = 0; ks < 2; ++ks) {
            half8 bf[4];
#pragma unroll
            for (int fn = 0; fn < 4; ++fn) {
                int row = fn * 16 + l16;
                int sidx = (ks * 4 + lhi) ^ (row & 7);
                bf[fn] = *(const half8*)(&lsB[cur][0] + row * 64 + sidx * 8);
            }
#pragma unroll
            for (int fm = 0; fm < 4; ++fm) {
                int row = wm + fm * 16 + l16;
                int sidx = (ks * 4 + lhi) ^ (row & 7);
                half8 af = *(const half8*)(&lsA[cur][0] + row * 64 + sidx * 8);
#pragma unroll
                for (int fn = 0; fn < 4; ++fn)
                    acc[fm][fn] = __builtin_amdgcn_mfma_f32_16x16x32_f16(bf[fn], af, acc[fm][fn], 0, 0, 0);
            }
        }
    }

    float bv[4][4];
#pragma unroll
    for (int fn = 0; fn < 4; ++fn)
#pragma unroll
        for (int rr = 0; rr < 4; ++rr) {
            int nn = fn * 16 + lhi * 4 + rr;
            bv[fn][rr] = (nn < 40) ? bias[nn] : 0.f;
        }

#pragma unroll
    for (int fm = 0; fm < 4; ++fm) {
        int m = brow + wm + fm * 16 + l16;
        float v[4][4];
        float mx = -INFINITY;
#pragma unroll
        for (int fn = 0; fn < 4; ++fn)
#pragma unroll
            for (int rr = 0; rr < 4; ++rr) {
                int nn = fn * 16 + lhi * 4 + rr;
                v[fn][rr] = acc[fm][fn][rr] + bv[fn][rr];
                if (nn < 40) mx = fmaxf(mx, v[fn][rr]);
            }
        mx = fmaxf(mx, __shfl_xor(mx, 16));
        mx = fmaxf(mx, __shfl_xor(mx, 32));
        float s = 0.f;
#pragma unroll
        for (int fn = 0; fn < 3; ++fn)
#pragma unroll
            for (int rr = 0; rr < 4; ++rr) {
                int nn = fn * 16 + lhi * 4 + rr;
                if (nn < 40) s += __expf(v[fn][rr] - mx);
            }
        s += __shfl_xor(s, 16);
        s += __shfl_xor(s, 32);
        float ls = __logf(s);
        if (m < M) {
#pragma unroll
            for (int fn = 0; fn < 3; ++fn)
#pragma unroll
                for (int rr = 0; rr < 4; ++rr) {
                    int nn = fn * 16 + lhi * 4 + rr;
                    if (nn < 40) out[(size_t)m * 40 + nn] = v[fn][rr] - mx - ls;
                }
        }
    }
}

// ------------------------------ host --------------------------------------

extern "C" void kernel_launch(void* const* d_in, const int* in_sizes, int n_in,
                              void* d_out, int out_size, void* d_ws, size_t ws_size,
                              hipStream_t stream) {
    const float* x   = (const float*)d_in[0];
    const int*   ei  = (const int*)d_in[1];
    const float* ea  = (const float*)d_in[2];
    const float* W1  = (const float*)d_in[3];  const float* b1  = (const float*)d_in[4];
    const float* W2  = (const float*)d_in[5];  const float* b2  = (const float*)d_in[6];
    const float* W3  = (const float*)d_in[7];  const float* b3  = (const float*)d_in[8];
    const float* fW1 = (const float*)d_in[9];  const float* fb1 = (const float*)d_in[10];
    const float* fW2 = (const float*)d_in[11]; const float* fb2 = (const float*)d_in[12];

    int n = in_sizes[0] / 64;
    int E = in_sizes[1] / 2;
    int Mpad = ((n + 255) / 256) * 256;
    const int* src = ei;
    const int* dst = ei + E;
    float* out = (float*)d_out;

    char* p = (char*)d_ws;
    auto alloc = [&](size_t bytes) -> char* {
        char* r = p;
        p += (bytes + 255) & ~(size_t)255;
        return r;
    };
    int nb256 = (n + 255) / 256;
    u64*   packed   = (u64*)alloc((size_t)n * 8);
    float* dinv     = (float*)alloc((size_t)n * 4);
    int*   cnt      = (int*)alloc((size_t)n * 4);
    int*   rowptr   = (int*)alloc((size_t)(n + 1) * 4);
    int*   bsum     = (int*)alloc((size_t)nb256 * 4);
    int*   eslot    = (int*)alloc((size_t)E * 4);
    int*   csr_src  = (int*)alloc((size_t)E * 4);
    f16*   csr_norm = (f16*)alloc((size_t)E * 2);
    f16* XH  = (f16*)alloc((size_t)Mpad * 64 * 2);
    f16* W1T = (f16*)alloc((size_t)128 * 64 * 2);
    f16* W2T = (f16*)alloc((size_t)256 * 128 * 2);
    f16* W3T = (f16*)alloc((size_t)512 * 256 * 2);
    f16* F1T = (f16*)alloc((size_t)512 * 512 * 2);
    f16* F2T = (f16*)alloc((size_t)64 * 512 * 2);
    f16* AGG = (f16*)alloc((size_t)Mpad * 256 * 2);
    f16* HA  = (f16*)alloc((size_t)Mpad * 512 * 2);
    f16* HB  = (f16*)alloc((size_t)Mpad * 512 * 2);

    const int tb = 256;
    int eB = (E + tb - 1) / tb;
    int e4B = (E / 4 + tb - 1) / tb + 1;
    auto aggB = [&](int npw) {
        long waves = (n + npw - 1) / npw;
        return (int)((waves * 64 + tb - 1) / tb);
    };

    // fused prep: packed init + x-cast + coalesced weight transposes
    {
        PrepArgs a;
        a.packed = packed; a.n = n;
        a.x = x; a.xh = XH; a.xt4 = n * 16;
        a.W[0] = W1;  a.WT[0] = W1T; a.lgK[0] = 6; a.lgNp[0] = 7; a.N[0] = 128;
        a.W[1] = W2;  a.WT[1] = W2T; a.lgK[1] = 7; a.lgNp[1] = 8; a.N[1] = 256;
        a.W[2] = W3;  a.WT[2] = W3T; a.lgK[2] = 8; a.lgNp[2] = 9; a.N[2] = 512;
        a.W[3] = fW1; a.WT[3] = F1T; a.lgK[3] = 9; a.lgNp[3] = 9; a.N[3] = 512;
        a.W[4] = fW2; a.WT[4] = F2T; a.lgK[4] = 9; a.lgNp[4] = 6; a.N[4] = 40;
        a.off[0] = 0;
        a.off[1] = a.off[0] + 128 * 64;
        a.off[2] = a.off[1] + 256 * 128;
        a.off[3] = a.off[2] + 512 * 256;
        a.off[4] = a.off[3] + 512 * 512;
        a.off[5] = a.off[4] + 64 * 512;
        int tot = a.n + a.xt4 + a.off[5];
        k_prep<<<(tot + tb - 1) / tb, tb, 0, stream>>>(a);
    }

    // graph prep
    k_edge1<<<e4B, tb, 0, stream>>>(dst, ea, packed, eslot, E);
    k_dinv_scan1<<<nb256, tb, 0, stream>>>(packed, dinv, cnt, bsum, n);
    k_scan23<<<nb256, tb, 0, stream>>>(cnt, bsum, rowptr, n, E);
    k_fill<<<eB, tb, 0, stream>>>(src, dst, ea, eslot, dinv, rowptr, csr_src, csr_norm, E);

    // 128x128-tile GEMM for all conv/fc layers
    auto mm = [&](const f16* a, const f16* bt, const float* bias, f16* ch, int N, int K) {
        int nB2 = N / 128;
        int nwg = (Mpad / 128) * nB2;
        k_mm<true><<<nwg, 256, 0, stream>>>(a, bt, bias, ch, n, N, K, nB2, nwg);
    };

    // conv1: agg(xh)[.,64] -> @W1 relu -> HA[.,128]
    k_agg<64><<<aggB(8), tb, 0, stream>>>(XH, dinv, rowptr, csr_src, csr_norm, AGG, n);
    mm(AGG, W1T, b1, HA, 128, 64);
    // conv2: agg(HA)[.,128] -> @W2 relu -> HB[.,256]
    k_agg<128><<<aggB(4), tb, 0, stream>>>(HA, dinv, rowptr, csr_src, csr_norm, AGG, n);
    mm(AGG, W2T, b2, HB, 256, 128);
    // conv3: agg(HB)[.,256] -> @W3 relu -> HA[.,512]
    k_agg<256><<<aggB(2), tb, 0, stream>>>(HB, dinv, rowptr, csr_src, csr_norm, AGG, n);
    mm(AGG, W3T, b3, HA, 512, 256);
    // fc1: HA @ fW1 relu -> HB[.,512]
    mm(HA, F1T, fb1, HB, 512, 512);
    // fc2 + log_softmax fused -> out
    k_mmfc2<<<Mpad / 256, 256, 0, stream>>>(HB, F2T, fb2, out, n, 512);
}

// Round 15
// 197.598 us; speedup vs baseline: 1.0324x; 1.0324x over previous
//
#include <hip/hip_runtime.h>
#include <cstdint>
#include <cstddef>

// ---------------------------------------------------------------------------
// GCN 3-conv + MLP head. FP16 single-product MFMA GEMMs (f32 accumulate),
// f16 activations, aggregate-before-linear (A(xW) == (Ax)W, Fin<Fout).
// All conv/fc GEMMs: 128x128 4-wave tiles. fc2 GEMM fuses bias+log_softmax.
// Single packed-u64 degree histogram; CSR slots from atomic returns;
// atomic-free fill; f16 csr_norm; coalesced-read weight transpose.
// Round 15: agg reverted to single-acc 4-edge unroll (round-14's dual-acc
// 8-edge isolated as a -5us regression: VGPR/occupancy cost > ILP gain).
// ---------------------------------------------------------------------------

typedef _Float16 f16;
typedef _Float16 half8 __attribute__((ext_vector_type(8)));
typedef _Float16 half4 __attribute__((ext_vector_type(4)));
typedef float v4f __attribute__((ext_vector_type(4)));
typedef unsigned long long u64;

__device__ inline void gload_lds16(const void* g, void* l) {
    __builtin_amdgcn_global_load_lds(
        (const __attribute__((address_space(1))) unsigned int*)g,
        (__attribute__((address_space(3))) unsigned int*)l, 16, 0, 0);
}

// ------------------------------ graph prep --------------------------------

// one packed atomic per edge; old value -> CSR slot within dst bucket
__global__ __launch_bounds__(256) void k_edge1(const int* __restrict__ dst, const float* __restrict__ ew,
                                               u64* __restrict__ packed, int* __restrict__ eslot, int E) {
    int t = blockIdx.x * blockDim.x + threadIdx.x;
    int e0 = t * 4;
    if (e0 + 3 < E) {
        int4 d4 = *(const int4*)(dst + e0);
        float4 w4 = *(const float4*)(ew + e0);
        u64 a0 = ((u64)__float2uint_rn(w4.x * 1048576.f) << 24) | 1ULL;
        u64 a1 = ((u64)__float2uint_rn(w4.y * 1048576.f) << 24) | 1ULL;
        u64 a2 = ((u64)__float2uint_rn(w4.z * 1048576.f) << 24) | 1ULL;
        u64 a3 = ((u64)__float2uint_rn(w4.w * 1048576.f) << 24) | 1ULL;
        u64 o0 = atomicAdd(&packed[d4.x], a0);
        u64 o1 = atomicAdd(&packed[d4.y], a1);
        u64 o2 = atomicAdd(&packed[d4.z], a2);
        u64 o3 = atomicAdd(&packed[d4.w], a3);
        int4 s;
        s.x = (int)(o0 & 0xFFFFFF); s.y = (int)(o1 & 0xFFFFFF);
        s.z = (int)(o2 & 0xFFFFFF); s.w = (int)(o3 & 0xFFFFFF);
        *(int4*)(eslot + e0) = s;
    } else {
        for (int e = e0; e < E; ++e) {
            u64 a = ((u64)__float2uint_rn(ew[e] * 1048576.f) << 24) | 1ULL;
            u64 o = atomicAdd(&packed[dst[e]], a);
            eslot[e] = (int)(o & 0xFFFFFF);
        }
    }
}

// fused: dinv (Newton-refined rsqrt of unpacked degree) + per-block cnt sums
__global__ __launch_bounds__(256) void k_dinv_scan1(const u64* __restrict__ packed,
                                                    float* __restrict__ dinv, int* __restrict__ cnt,
                                                    int* __restrict__ bsum, int n) {
    int i = blockIdx.x * 256 + threadIdx.x;
    int c = 0;
    if (i < n) {
        u64 pk = packed[i];
        c = (int)(pk & 0xFFFFFF);
        float d = 1.0f + (float)(pk >> 24) * (1.0f / 1048576.f);  // self-loop + sum(ew)
        float r = rsqrtf(d);
        r = r * (1.5f - 0.5f * d * r * r);
        dinv[i] = r;
        cnt[i] = c;
    }
    int v = c;
#pragma unroll
    for (int o = 32; o; o >>= 1) v += __shfl_xor(v, o);
    __shared__ int s[4];
    if ((threadIdx.x & 63) == 0) s[threadIdx.x >> 6] = v;
    __syncthreads();
    if (threadIdx.x == 0) bsum[blockIdx.x] = s[0] + s[1] + s[2] + s[3];
}

// 256-thread inclusive block scan (shfl wave scan + LDS wave offsets).
__device__ inline int block_scan_incl(int v) {
    __shared__ int ws[4];
    int lane = threadIdx.x & 63, w = threadIdx.x >> 6;
#pragma unroll
    for (int off = 1; off < 64; off <<= 1) {
        int t = __shfl_up(v, off);
        if (lane >= off) v += t;
    }
    if (lane == 63) ws[w] = v;
    __syncthreads();
    int add = 0;
#pragma unroll
    for (int i = 0; i < 4; ++i) add += (i < w) ? ws[i] : 0;
    __syncthreads();
    return v + add;
}

// fused scan2+scan3: each block sums bsum[0..blk) itself (one wave), then
// local scan + offset -> rowptr. No inter-block communication.
__global__ __launch_bounds__(256) void k_scan23(const int* __restrict__ cnt, const int* __restrict__ bsum,
                                                int* __restrict__ rowptr, int n, int E) {
    int blk = blockIdx.x, tid = threadIdx.x;
    int i = blk * 256 + tid;
    __shared__ int spre;
    if (tid < 64) {
        int s = 0;
        for (int j = tid; j < blk; j += 64) s += bsum[j];
#pragma unroll
        for (int o = 32; o; o >>= 1) s += __shfl_xor(s, o);
        if (tid == 0) spre = s;
    }
    __syncthreads();
    int v = (i < n) ? cnt[i] : 0;
    int incl = block_scan_incl(v);
    if (i < n) rowptr[i] = spre + incl - v;
    if (i == n - 1) rowptr[n] = E;
}

// atomic-free CSR fill using precomputed slots; f16 norm
__global__ __launch_bounds__(256) void k_fill(const int* __restrict__ src, const int* __restrict__ dst,
                                              const float* __restrict__ ew, const int* __restrict__ eslot,
                                              const float* __restrict__ dinv, const int* __restrict__ rowptr,
                                              int* __restrict__ csr_src, f16* __restrict__ csr_norm, int E) {
    int e = blockIdx.x * blockDim.x + threadIdx.x;
    if (e < E) {
        int d = dst[e], s = src[e];
        int idx = rowptr[d] + eslot[e];
        csr_src[idx] = s;
        csr_norm[idx] = (f16)(dinv[s] * ew[e] * dinv[d]);
    }
}

// fused: packed init + x f32->f16 cast + 5 weight transposes W[K,N]->WT[Np,K].
// Transpose reads COALESCED (k=li/Np, nr=li%Np); strided f16 writes merge in L2.
struct PrepArgs {
    u64* packed; int n;
    const float* x; f16* xh; int xt4;
    const float* W[5]; f16* WT[5];
    int lgK[5]; int lgNp[5]; int N[5]; int off[6];
};
__global__ __launch_bounds__(256) void k_prep(PrepArgs a) {
    int i = blockIdx.x * 256 + threadIdx.x;
    if (i < a.n) { a.packed[i] = 0ULL; return; }
    int j = i - a.n;
    if (j < a.xt4) {
        float4 v = *(const float4*)(a.x + (size_t)j * 4);
        half4 h = {(f16)v.x, (f16)v.y, (f16)v.z, (f16)v.w};
        *(half4*)(a.xh + (size_t)j * 4) = h;
        return;
    }
    int w = j - a.xt4;
#pragma unroll
    for (int s = 0; s < 5; ++s) {
        if (w >= a.off[s] && w < a.off[s + 1]) {
            int li = w - a.off[s];
            int Np = 1 << a.lgNp[s];
            int K = 1 << a.lgK[s];
            int k = li >> a.lgNp[s], nr = li & (Np - 1);
            float v = (nr < a.N[s]) ? a.W[s][(size_t)k * a.N[s] + nr] : 0.f;
            a.WT[s][(size_t)nr * K + k] = (f16)v;
        }
    }
}

// ------------------------------ aggregation -------------------------------
// out[i,:] = dinv[i]^2*h[i,:] + sum_j norm_j*h[src_j,:]; f16 in/out, f32 acc.
// Single accumulator, 4-edge unroll (measured best: round-13 config).
template <int F>
__global__ __launch_bounds__(256) void k_agg(const f16* __restrict__ h,
                                             const float* __restrict__ dinv, const int* __restrict__ rowptr,
                                             const int* __restrict__ csr_src, const f16* __restrict__ csr_norm,
                                             f16* __restrict__ o, int n) {
    constexpr int LPN = F / 8;
    constexpr int NPW = 64 / LPN;
    int wave = (int)((blockIdx.x * (unsigned)blockDim.x + threadIdx.x) >> 6);
    int lane = threadIdx.x & 63;
    int grp = lane / LPN, lin = lane % LPN;
    int node = wave * NPW + grp;
    if (node >= n) return;
    float di = dinv[node], w0 = di * di;
    float acc[8];
#pragma unroll
    for (int i = 0; i < 8; ++i) acc[i] = 0.f;

    auto gat = [&](int s, float w) {
        half8 x = *(const half8*)(h + (size_t)s * F + lin * 8);
#pragma unroll
        for (int i = 0; i < 8; ++i) acc[i] += w * (float)x[i];
    };

    gat(node, w0);
    int beg = rowptr[node], end = rowptr[node + 1];
    int j = beg;
    for (; j + 3 < end; j += 4) {  // 4 independent gathers in flight
        int s0 = csr_src[j], s1 = csr_src[j + 1], s2 = csr_src[j + 2], s3 = csr_src[j + 3];
        float u0 = (float)csr_norm[j], u1 = (float)csr_norm[j + 1];
        float u2 = (float)csr_norm[j + 2], u3 = (float)csr_norm[j + 3];
        gat(s0, u0); gat(s1, u1); gat(s2, u2); gat(s3, u3);
    }
    for (; j < end; ++j) gat(csr_src[j], (float)csr_norm[j]);

    half8 v;
#pragma unroll
    for (int i = 0; i < 8; ++i) v[i] = (f16)acc[i];
    *(half8*)(o + (size_t)node * F + (size_t)lin * 8) = v;
}

// ------------------------------ MFMA GEMM ----------------------------------
// 128x128 tile, 4 waves 2x2. A,B via global_load_lds (XOR-swizzled both
// sides), double-buffered, one barrier per k-step. 64KB LDS -> 2 blocks/CU.
// Operand-swapped MFMA -> C^T frags -> coalesced 8B stores.
template <bool RELU>
__global__ __launch_bounds__(256) void k_mm(const f16* __restrict__ A, const f16* __restrict__ BT,
                                            const float* __restrict__ bias, f16* __restrict__ Ch,
                                            int M, int N, int K, int nB, int nwg) {
    __shared__ f16 lsA[2][128 * 64];
    __shared__ f16 lsB[2][128 * 64];
    int wg = blockIdx.x;
    int q = nwg >> 3, r = nwg & 7;
    int xcd = wg & 7, lin = wg >> 3;
    int wgs = (xcd < r) ? (xcd * (q + 1) + lin) : (r * (q + 1) + (xcd - r) * q + lin);
    int bm = wgs / nB, bn = wgs % nB;

    int tid = threadIdx.x;
    int lane = tid & 63, wid = tid >> 6;
    int l16 = lane & 15, lhi = lane >> 4;
    int wm = (wid >> 1) * 64, wn = (wid & 1) * 64;
    int brow = bm * 128, bcol = bn * 128;

    v4f acc[4][4] = {};

    auto stageA = [&](int buf, int k0) {
#pragma unroll
        for (int it = 0; it < 4; ++it) {
            int b = it * 4096 + tid * 16;
            int row = b >> 7;
            int s = ((b >> 4) & 7) ^ (row & 7);
            gload_lds16(A + (size_t)(brow + row) * K + k0 + s * 8, ((char*)&lsA[buf][0]) + b);
        }
    };
    auto stageB = [&](int buf, int k0) {
#pragma unroll
        for (int it = 0; it < 4; ++it) {
            int b = it * 4096 + tid * 16;
            int row = b >> 7;
            int s = ((b >> 4) & 7) ^ (row & 7);
            gload_lds16(BT + (size_t)(bcol + row) * K + k0 + s * 8, ((char*)&lsB[buf][0]) + b);
        }
    };

    int nk = K >> 6;
    stageA(0, 0);
    stageB(0, 0);
    for (int kt = 0; kt < nk; ++kt) {
        int cur = kt & 1;
        __syncthreads();  // buf[cur] DMA drained; prior LDS reads done
        if (kt + 1 < nk) { stageA(cur ^ 1, (kt + 1) << 6); stageB(cur ^ 1, (kt + 1) << 6); }
#pragma unroll
        for (int ks = 0; ks < 2; ++ks) {
            half8 bf[4];
#pragma unroll
            for (int fn = 0; fn < 4; ++fn) {
                int row = wn + fn * 16 + l16;
                int sidx = (ks * 4 + lhi) ^ (row & 7);
                bf[fn] = *(const half8*)(&lsB[cur][0] + row * 64 + sidx * 8);
            }
#pragma unroll
            for (int fm = 0; fm < 4; ++fm) {
                int row = wm + fm * 16 + l16;
                int sidx = (ks * 4 + lhi) ^ (row & 7);
                half8 af = *(const half8*)(&lsA[cur][0] + row * 64 + sidx * 8);
#pragma unroll
                for (int fn = 0; fn < 4; ++fn)
                    acc[fm][fn] = __builtin_amdgcn_mfma_f32_16x16x32_f16(bf[fn], af, acc[fm][fn], 0, 0, 0);
            }
        }
    }
#pragma unroll
    for (int fm = 0; fm < 4; ++fm) {
        int m = brow + wm + fm * 16 + l16;
        if (m >= M) continue;
#pragma unroll
        for (int fn = 0; fn < 4; ++fn) {
            int nb = bcol + wn + fn * 16 + lhi * 4;
            v4f bv = *(const v4f*)(bias + nb);
            v4f v = acc[fm][fn] + bv;
            if (RELU) {
#pragma unroll
                for (int rr = 0; rr < 4; ++rr) v[rr] = fmaxf(v[rr], 0.f);
            }
            half4 hv = {(f16)v[0], (f16)v[1], (f16)v[2], (f16)v[3]};
            *(half4*)(Ch + (size_t)m * N + nb) = hv;
        }
    }
}

// ----------------------- fc2 GEMM + log_softmax ---------------------------
__global__ __launch_bounds__(256) void k_mmfc2(const f16* __restrict__ A, const f16* __restrict__ BT,
                                               const float* __restrict__ bias, float* __restrict__ out,
                                               int M, int K) {
    __shared__ f16 lsA[2][256 * 64];
    __shared__ f16 lsB[2][64 * 64];
    int bm = blockIdx.x;
    int tid = threadIdx.x;
    int lane = tid & 63, wid = tid >> 6;
    int l16 = lane & 15, lhi = lane >> 4;
    int wm = wid * 64;
    int brow = bm * 256;

    v4f acc[4][4] = {};

    auto stageA = [&](int buf, int k0) {
#pragma unroll
        for (int it = 0; it < 8; ++it) {
            int b = it * 4096 + tid * 16;
            int row = b >> 7;
            int s = ((b >> 4) & 7) ^ (row & 7);
            gload_lds16(A + (size_t)(brow + row) * K + k0 + s * 8, ((char*)&lsA[buf][0]) + b);
        }
    };
    auto stageB = [&](int buf, int k0) {
#pragma unroll
        for (int it = 0; it < 2; ++it) {
            int b = it * 4096 + tid * 16;
            int row = b >> 7;
            int s = ((b >> 4) & 7) ^ (row & 7);
            gload_lds16(BT + (size_t)row * K + k0 + s * 8, ((char*)&lsB[buf][0]) + b);
        }
    };

    int nk = K >> 6;
    stageA(0, 0);
    stageB(0, 0);
    for (int kt = 0; kt < nk; ++kt) {
        int cur = kt & 1;
        __syncthreads();
        if (kt + 1 < nk) { stageA(cur ^ 1, (kt + 1) << 6); stageB(cur ^ 1, (kt + 1) << 6); }
#pragma unroll
        for (int ks = 0; ks < 2; ++ks) {
            half8 bf[4];
#pragma unroll
            for (int fn = 0; fn < 4; ++fn) {
                int row = fn * 16 + l16;
                int sidx = (ks * 4 + lhi) ^ (row & 7);
                bf[fn] = *(const half8*)(&lsB[cur][0] + row * 64 + sidx * 8);
            }
#pragma unroll
            for (int fm = 0; fm < 4; ++fm) {
                int row = wm + fm * 16 + l16;
                int sidx = (ks * 4 + lhi) ^ (row & 7);
                half8 af = *(const half8*)(&lsA[cur][0] + row * 64 + sidx * 8);
#pragma unroll
                for (int fn = 0; fn < 4; ++fn)
                    acc[fm][fn] = __builtin_amdgcn_mfma_f32_16x16x32_f16(bf[fn], af, acc[fm][fn], 0, 0, 0);
            }
        }
    }

    float bv[4][4];
#pragma unroll
    for (int fn = 0; fn < 4; ++fn)
#pragma unroll
        for (int rr = 0; rr < 4; ++rr) {
            int nn = fn * 16 + lhi * 4 + rr;
            bv[fn][rr] = (nn < 40) ? bias[nn] : 0.f;
        }

#pragma unroll
    for (int fm = 0; fm < 4; ++fm) {
        int m = brow + wm + fm * 16 + l16;
        float v[4][4];
        float mx = -INFINITY;
#pragma unroll
        for (int fn = 0; fn < 4; ++fn)
#pragma unroll
            for (int rr = 0; rr < 4; ++rr) {
                int nn = fn * 16 + lhi * 4 + rr;
                v[fn][rr] = acc[fm][fn][rr] + bv[fn][rr];
                if (nn < 40) mx = fmaxf(mx, v[fn][rr]);
            }
        mx = fmaxf(mx, __shfl_xor(mx, 16));
        mx = fmaxf(mx, __shfl_xor(mx, 32));
        float s = 0.f;
#pragma unroll
        for (int fn = 0; fn < 3; ++fn)
#pragma unroll
            for (int rr = 0; rr < 4; ++rr) {
                int nn = fn * 16 + lhi * 4 + rr;
                if (nn < 40) s += __expf(v[fn][rr] - mx);
            }
        s += __shfl_xor(s, 16);
        s += __shfl_xor(s, 32);
        float ls = __logf(s);
        if (m < M) {
#pragma unroll
            for (int fn = 0; fn < 3; ++fn)
#pragma unroll
                for (int rr = 0; rr < 4; ++rr) {
                    int nn = fn * 16 + lhi * 4 + rr;
                    if (nn < 40) out[(size_t)m * 40 + nn] = v[fn][rr] - mx - ls;
                }
        }
    }
}

// ------------------------------ host --------------------------------------

extern "C" void kernel_launch(void* const* d_in, const int* in_sizes, int n_in,
                              void* d_out, int out_size, void* d_ws, size_t ws_size,
                              hipStream_t stream) {
    const float* x   = (const float*)d_in[0];
    const int*   ei  = (const int*)d_in[1];
    const float* ea  = (const float*)d_in[2];
    const float* W1  = (const float*)d_in[3];  const float* b1  = (const float*)d_in[4];
    const float* W2  = (const float*)d_in[5];  const float* b2  = (const float*)d_in[6];
    const float* W3  = (const float*)d_in[7];  const float* b3  = (const float*)d_in[8];
    const float* fW1 = (const float*)d_in[9];  const float* fb1 = (const float*)d_in[10];
    const float* fW2 = (const float*)d_in[11]; const float* fb2 = (const float*)d_in[12];

    int n = in_sizes[0] / 64;
    int E = in_sizes[1] / 2;
    int Mpad = ((n + 255) / 256) * 256;
    const int* src = ei;
    const int* dst = ei + E;
    float* out = (float*)d_out;

    char* p = (char*)d_ws;
    auto alloc = [&](size_t bytes) -> char* {
        char* r = p;
        p += (bytes + 255) & ~(size_t)255;
        return r;
    };
    int nb256 = (n + 255) / 256;
    u64*   packed   = (u64*)alloc((size_t)n * 8);
    float* dinv     = (float*)alloc((size_t)n * 4);
    int*   cnt      = (int*)alloc((size_t)n * 4);
    int*   rowptr   = (int*)alloc((size_t)(n + 1) * 4);
    int*   bsum     = (int*)alloc((size_t)nb256 * 4);
    int*   eslot    = (int*)alloc((size_t)E * 4);
    int*   csr_src  = (int*)alloc((size_t)E * 4);
    f16*   csr_norm = (f16*)alloc((size_t)E * 2);
    f16* XH  = (f16*)alloc((size_t)Mpad * 64 * 2);
    f16* W1T = (f16*)alloc((size_t)128 * 64 * 2);
    f16* W2T = (f16*)alloc((size_t)256 * 128 * 2);
    f16* W3T = (f16*)alloc((size_t)512 * 256 * 2);
    f16* F1T = (f16*)alloc((size_t)512 * 512 * 2);
    f16* F2T = (f16*)alloc((size_t)64 * 512 * 2);
    f16* AGG = (f16*)alloc((size_t)Mpad * 256 * 2);
    f16* HA  = (f16*)alloc((size_t)Mpad * 512 * 2);
    f16* HB  = (f16*)alloc((size_t)Mpad * 512 * 2);

    const int tb = 256;
    int eB = (E + tb - 1) / tb;
    int e4B = (E / 4 + tb - 1) / tb + 1;
    auto aggB = [&](int npw) {
        long waves = (n + npw - 1) / npw;
        return (int)((waves * 64 + tb - 1) / tb);
    };

    // fused prep: packed init + x-cast + coalesced weight transposes
    {
        PrepArgs a;
        a.packed = packed; a.n = n;
        a.x = x; a.xh = XH; a.xt4 = n * 16;
        a.W[0] = W1;  a.WT[0] = W1T; a.lgK[0] = 6; a.lgNp[0] = 7; a.N[0] = 128;
        a.W[1] = W2;  a.WT[1] = W2T; a.lgK[1] = 7; a.lgNp[1] = 8; a.N[1] = 256;
        a.W[2] = W3;  a.WT[2] = W3T; a.lgK[2] = 8; a.lgNp[2] = 9; a.N[2] = 512;
        a.W[3] = fW1; a.WT[3] = F1T; a.lgK[3] = 9; a.lgNp[3] = 9; a.N[3] = 512;
        a.W[4] = fW2; a.WT[4] = F2T; a.lgK[4] = 9; a.lgNp[4] = 6; a.N[4] = 40;
        a.off[0] = 0;
        a.off[1] = a.off[0] + 128 * 64;
        a.off[2] = a.off[1] + 256 * 128;
        a.off[3] = a.off[2] + 512 * 256;
        a.off[4] = a.off[3] + 512 * 512;
        a.off[5] = a.off[4] + 64 * 512;
        int tot = a.n + a.xt4 + a.off[5];
        k_prep<<<(tot + tb - 1) / tb, tb, 0, stream>>>(a);
    }

    // graph prep
    k_edge1<<<e4B, tb, 0, stream>>>(dst, ea, packed, eslot, E);
    k_dinv_scan1<<<nb256, tb, 0, stream>>>(packed, dinv, cnt, bsum, n);
    k_scan23<<<nb256, tb, 0, stream>>>(cnt, bsum, rowptr, n, E);
    k_fill<<<eB, tb, 0, stream>>>(src, dst, ea, eslot, dinv, rowptr, csr_src, csr_norm, E);

    // 128x128-tile GEMM for all conv/fc layers
    auto mm = [&](const f16* a, const f16* bt, const float* bias, f16* ch, int N, int K) {
        int nB2 = N / 128;
        int nwg = (Mpad / 128) * nB2;
        k_mm<true><<<nwg, 256, 0, stream>>>(a, bt, bias, ch, n, N, K, nB2, nwg);
    };

    // conv1: agg(xh)[.,64] -> @W1 relu -> HA[.,128]
    k_agg<64><<<aggB(8), tb, 0, stream>>>(XH, dinv, rowptr, csr_src, csr_norm, AGG, n);
    mm(AGG, W1T, b1, HA, 128, 64);
    // conv2: agg(HA)[.,128] -> @W2 relu -> HB[.,256]
    k_agg<128><<<aggB(4), tb, 0, stream>>>(HA, dinv, rowptr, csr_src, csr_norm, AGG, n);
    mm(AGG, W2T, b2, HB, 256, 128);
    // conv3: agg(HB)[.,256] -> @W3 relu -> HA[.,512]
    k_agg<256><<<aggB(2), tb, 0, stream>>>(HB, dinv, rowptr, csr_src, csr_norm, AGG, n);
    mm(AGG, W3T, b3, HA, 512, 256);
    // fc1: HA @ fW1 relu -> HB[.,512]
    mm(HA, F1T, fb1, HB, 512, 512);
    // fc2 + log_softmax fused -> out
    k_mmfc2<<<Mpad / 256, 256, 0, stream>>>(HB, F2T, fb2, out, n, 512);
}